// Round 1
// baseline (1360.666 us; speedup 1.0000x reference)
//
#include <hip/hip_runtime.h>
#include <hip/hip_bf16.h>

// GCN: 3x (GEMM 64x64 -> sym-norm gather/scatter) -> mean-pool -> linear.
// N=100000 nodes, E=1200000 edges, 128 graphs, D=64, classes=10.

#define N_NODES 100000
#define N_EDGES 1200000
#define N_GRAPHS 128
#define D 64
#define N_CLASSES 10

// ---- init: deg=1 (self loop), zero pool accumulators ----
__global__ void init_k(float* __restrict__ deg, float* __restrict__ gsum,
                       float* __restrict__ cnt, int n) {
    int i = blockIdx.x * 256 + threadIdx.x;
    if (i < n) deg[i] = 1.0f;
    if (i < N_GRAPHS * D) gsum[i] = 0.0f;
    if (i < N_GRAPHS) cnt[i] = 0.0f;
}

// ---- deg[c] += 1 per edge ----
__global__ void degcnt_k(const int* __restrict__ col, float* __restrict__ deg, int E) {
    int e = blockIdx.x * 256 + threadIdx.x;
    if (e < E) atomicAdd(&deg[col[e]], 1.0f);
}

// ---- deg -> rsqrt(deg) in-place ----
__global__ void dinv_k(float* __restrict__ deg, int n) {
    int i = blockIdx.x * 256 + threadIdx.x;
    if (i < n) deg[i] = rsqrtf(deg[i]);
}

// ---- H = relu?(X) @ W  (W is [64][64] row-major, staged in LDS) ----
// block = 256 threads = 4 waves; each wave computes one output row.
__global__ void gemm_k(const float* __restrict__ X, const float* __restrict__ W,
                       float* __restrict__ H, int n, int relu_in) {
    __shared__ float Wl[D * D];
    int tid = threadIdx.x;
    for (int i = tid; i < D * D; i += 256) Wl[i] = W[i];
    __syncthreads();
    int wave = tid >> 6, lane = tid & 63;
    int row = blockIdx.x * 4 + wave;
    if (row >= n) return;
    float xv = X[row * D + lane];
    if (relu_in) xv = fmaxf(xv, 0.0f);
    float acc = 0.0f;
#pragma unroll
    for (int k = 0; k < D; ++k)
        acc += __shfl(xv, k) * Wl[k * D + lane];
    H[row * D + lane] = acc;
}

// ---- O[i][d] = b[d] + H[i][d]*dinv[i]^2  (self-loop term + bias) ----
__global__ void init_out_k(const float* __restrict__ H, const float* __restrict__ dinv,
                           const float* __restrict__ b, float* __restrict__ O, int n) {
    int idx = blockIdx.x * 256 + threadIdx.x;
    if (idx >= n * D) return;
    int i = idx >> 6, d = idx & 63;
    float di = dinv[i];
    O[idx] = b[d] + H[idx] * di * di;
}

// ---- per edge: O[c][:] += H[r][:] * dinv[r]*dinv[c]  (wave per edge) ----
__global__ void edge_k(const int* __restrict__ row, const int* __restrict__ col,
                       const float* __restrict__ H, const float* __restrict__ dinv,
                       float* __restrict__ O, int E) {
    int e = blockIdx.x * 4 + (threadIdx.x >> 6);
    if (e >= E) return;
    int lane = threadIdx.x & 63;
    int r = row[e], c = col[e];
    float norm = dinv[r] * dinv[c];
    atomicAdd(&O[c * D + lane], H[r * D + lane] * norm);
}

// ---- mean-pool stage 1: run-length accumulate (batch is sorted) ----
#define POOL_CHUNK 256
__global__ void pool_k(const float* __restrict__ H, const int* __restrict__ batch,
                       float* __restrict__ gsum, float* __restrict__ cnt, int n) {
    int wid = blockIdx.x * 4 + (threadIdx.x >> 6);
    int lane = threadIdx.x & 63;
    int start = wid * POOL_CHUNK;
    if (start >= n) return;
    int end = min(start + POOL_CHUNK, n);
    int cur = batch[start];
    float acc = 0.0f;
    int run = 0;
    for (int i = start; i < end; ++i) {
        int b = batch[i];
        if (b != cur) {
            atomicAdd(&gsum[cur * D + lane], acc);
            if (lane == 0) atomicAdd(&cnt[cur], (float)run);
            cur = b; acc = 0.0f; run = 0;
        }
        acc += H[i * D + lane];
        ++run;
    }
    atomicAdd(&gsum[cur * D + lane], acc);
    if (lane == 0) atomicAdd(&cnt[cur], (float)run);
}

// ---- out[b][c] = (gsum[b]/cnt[b]) @ linW + linb ----
__global__ void final_k(const float* __restrict__ gsum, const float* __restrict__ cnt,
                        const float* __restrict__ linW, const float* __restrict__ linb,
                        float* __restrict__ out) {
    int tid = blockIdx.x * 256 + threadIdx.x;
    if (tid >= N_GRAPHS * N_CLASSES) return;
    int b = tid / N_CLASSES, c = tid % N_CLASSES;
    float inv = 1.0f / fmaxf(cnt[b], 1.0f);
    float acc = linb[c];
#pragma unroll
    for (int k = 0; k < D; ++k)
        acc += gsum[b * D + k] * inv * linW[k * N_CLASSES + c];
    out[tid] = acc;
}

extern "C" void kernel_launch(void* const* d_in, const int* in_sizes, int n_in,
                              void* d_out, int out_size, void* d_ws, size_t ws_size,
                              hipStream_t stream) {
    const float* x    = (const float*)d_in[0];
    const int*   ei   = (const int*)  d_in[1];   // [2][E] (JAX x64 off -> int32)
    const int*   batch= (const int*)  d_in[2];
    const float* W1   = (const float*)d_in[3];
    const float* b1   = (const float*)d_in[4];
    const float* W2   = (const float*)d_in[5];
    const float* b2   = (const float*)d_in[6];
    const float* W3   = (const float*)d_in[7];
    const float* b3   = (const float*)d_in[8];
    const float* linW = (const float*)d_in[9];
    const float* linb = (const float*)d_in[10];
    float* out = (float*)d_out;

    const int N = N_NODES, E = N_EDGES;
    const int* row = ei;
    const int* col = ei + E;

    // workspace layout (floats), offsets 256B-aligned
    float* ws   = (float*)d_ws;
    float* dinv = ws;                    // 100000 (pad to 100352)
    float* bufH = dinv + 100352;         // 6.4M  (GEMM output)
    float* bufA = bufH + (size_t)N * D;  // 6.4M  (layer output / next input)
    float* gsum = bufA + (size_t)N * D;  // 8192
    float* cnt  = gsum + N_GRAPHS * D;   // 128

    const int nb_nodes = (N + 255) / 256;          // 391
    const int nb_edges = (E + 255) / 256;          // 4688
    const int nb_rows  = (N + 3) / 4;              // 25000 (4 rows/block)
    const int nb_feat  = (N * D) / 256;            // 25000
    const int nb_epe   = (E + 3) / 4;              // 300000 (4 edges/block)
    const int nwaves   = (N + POOL_CHUNK - 1) / POOL_CHUNK;  // 391
    const int nb_pool  = (nwaves + 3) / 4;         // 98

    // degree (shared across layers)
    init_k<<<nb_nodes, 256, 0, stream>>>(dinv, gsum, cnt, N);
    degcnt_k<<<nb_edges, 256, 0, stream>>>(col, dinv, E);
    dinv_k<<<nb_nodes, 256, 0, stream>>>(dinv, N);

    // layer 1: x -> bufA
    gemm_k<<<nb_rows, 256, 0, stream>>>(x, W1, bufH, N, 0);
    init_out_k<<<nb_feat, 256, 0, stream>>>(bufH, dinv, b1, bufA, N);
    edge_k<<<nb_epe, 256, 0, stream>>>(row, col, bufH, dinv, bufA, E);

    // layer 2: relu(bufA) -> bufA
    gemm_k<<<nb_rows, 256, 0, stream>>>(bufA, W2, bufH, N, 1);
    init_out_k<<<nb_feat, 256, 0, stream>>>(bufH, dinv, b2, bufA, N);
    edge_k<<<nb_epe, 256, 0, stream>>>(row, col, bufH, dinv, bufA, E);

    // layer 3: relu(bufA) -> bufA (no relu after)
    gemm_k<<<nb_rows, 256, 0, stream>>>(bufA, W3, bufH, N, 1);
    init_out_k<<<nb_feat, 256, 0, stream>>>(bufH, dinv, b3, bufA, N);
    edge_k<<<nb_epe, 256, 0, stream>>>(row, col, bufH, dinv, bufA, E);

    // pool + classify
    pool_k<<<nb_pool, 256, 0, stream>>>(bufA, batch, gsum, cnt, N);
    final_k<<<(N_GRAPHS * N_CLASSES + 255) / 256, 256, 0, stream>>>(gsum, cnt, linW, linb, out);
}

// Round 5
// 581.437 us; speedup vs baseline: 2.3402x; 2.3402x over previous
//
#include <hip/hip_runtime.h>
#include <hip/hip_bf16.h>

// GCN: 3x (GEMM 64x64 -> sym-norm gather via CSR) -> mean-pool -> linear.
// N=100000 nodes, E=1200000 edges, 128 graphs, D=64, classes=10.
// R2: replace per-edge 256B float atomics with CSR build (int atomics) +
//     wave-per-node gather; fuse dinv into GEMM output, bias+self into gather.
// (R5 resubmit: R2/R3/R4 benches were broker timeouts, no data.)

#define N_NODES 100000
#define N_EDGES 1200000
#define N_GRAPHS 128
#define D 64
#define N_CLASSES 10

// ---- init: zero deg_int, total counter, pool accumulators ----
__global__ void init_k(int* __restrict__ deg, int* __restrict__ total,
                       float* __restrict__ gsum, float* __restrict__ cnt, int n) {
    int i = blockIdx.x * 256 + threadIdx.x;
    if (i < n) deg[i] = 0;
    if (i == 0) *total = 0;
    if (i < N_GRAPHS * D) gsum[i] = 0.0f;
    if (i < N_GRAPHS) cnt[i] = 0.0f;
}

// ---- deg[c]++ per edge (int atomics) ----
__global__ void degcnt_k(const int* __restrict__ col, int* __restrict__ deg, int E) {
    int e = blockIdx.x * 256 + threadIdx.x;
    if (e < E) atomicAdd(&deg[col[e]], 1);
}

// ---- per node: segment start via wave-scan + 1 atomic/wave; dinv ----
__global__ void offsets_k(const int* __restrict__ deg, int* __restrict__ cursor,
                          float* __restrict__ dinv, int* __restrict__ total, int n) {
    int i = blockIdx.x * 256 + threadIdx.x;
    int lane = threadIdx.x & 63;
    int v = (i < n) ? deg[i] : 0;
    int incl = v;
#pragma unroll
    for (int d = 1; d < 64; d <<= 1) {
        int t = __shfl_up(incl, d);
        if (lane >= d) incl += t;
    }
    int wsum = __shfl(incl, 63);
    int base = 0;
    if (lane == 63) base = atomicAdd(total, wsum);
    base = __shfl(base, 63);
    if (i < n) {
        cursor[i] = base + incl - v;                 // exclusive start
        dinv[i] = rsqrtf((float)(v + 1));            // +1 self loop
    }
}

// ---- fill CSR: csr[cursor[c]++] = r   (after this, cursor[c] = segment END) ----
__global__ void fill_k(const int* __restrict__ row, const int* __restrict__ col,
                       int* __restrict__ cursor, int* __restrict__ csr, int E) {
    int e = blockIdx.x * 256 + threadIdx.x;
    if (e < E) {
        int c = col[e];
        int pos = atomicAdd(&cursor[c], 1);
        csr[pos] = row[e];
    }
}

// ---- H'[r][:] = (relu?(X[r]) @ W) * dinv[r] ----
// W[:,lane] held in 64 VGPRs (loaded once per block); X broadcast via LDS.
__global__ __launch_bounds__(256) void gemm_k(
        const float* __restrict__ X, const float* __restrict__ W,
        const float* __restrict__ dinv, float* __restrict__ H, int n, int relu_in) {
    __shared__ float Xs[4][D];
    int tid = threadIdx.x, wave = tid >> 6, lane = tid & 63;
    float wcol[D];
#pragma unroll
    for (int k = 0; k < D; ++k) wcol[k] = W[k * D + lane];
    for (int row0 = blockIdx.x * 4; row0 < n; row0 += gridDim.x * 4) {
        int row = row0 + wave;
        if (row < n) {
            float xv = X[row * D + lane];
            if (relu_in) xv = fmaxf(xv, 0.0f);
            Xs[wave][lane] = xv;
            float acc = 0.0f;
#pragma unroll
            for (int k = 0; k < D; ++k) acc += Xs[wave][k] * wcol[k];
            H[row * D + lane] = acc * dinv[row];
        }
    }
}

// ---- gather: O[c] = b + dinv[c] * (H'[c] + sum_{r in N(c)} H'[r]) ----
__global__ void gather_k(const float* __restrict__ Hp, const int* __restrict__ csr,
                         const int* __restrict__ cursor, const int* __restrict__ deg,
                         const float* __restrict__ dinv, const float* __restrict__ b,
                         float* __restrict__ O, int n) {
    int c = blockIdx.x * 4 + (threadIdx.x >> 6);
    if (c >= n) return;
    int lane = threadIdx.x & 63;
    int end = cursor[c];              // cursor == end after fill_k
    int dg = deg[c];
    int j = end - dg;
    float acc = Hp[(size_t)c * D + lane];   // self term (already * dinv[c])
    for (; j + 4 <= end; j += 4) {
        int s0 = csr[j], s1 = csr[j + 1], s2 = csr[j + 2], s3 = csr[j + 3];
        float v0 = Hp[(size_t)s0 * D + lane];
        float v1 = Hp[(size_t)s1 * D + lane];
        float v2 = Hp[(size_t)s2 * D + lane];
        float v3 = Hp[(size_t)s3 * D + lane];
        acc += v0 + v1 + v2 + v3;
    }
    for (; j < end; ++j) acc += Hp[(size_t)csr[j] * D + lane];
    O[(size_t)c * D + lane] = b[lane] + dinv[c] * acc;
}

// ---- mean-pool stage 1: run-length accumulate (batch is sorted) ----
#define POOL_CHUNK 256
__global__ void pool_k(const float* __restrict__ H, const int* __restrict__ batch,
                       float* __restrict__ gsum, float* __restrict__ cnt, int n) {
    int wid = blockIdx.x * 4 + (threadIdx.x >> 6);
    int lane = threadIdx.x & 63;
    int start = wid * POOL_CHUNK;
    if (start >= n) return;
    int end = min(start + POOL_CHUNK, n);
    int cur = batch[start];
    float acc = 0.0f;
    int run = 0;
    for (int i = start; i < end; ++i) {
        int bb = batch[i];
        if (bb != cur) {
            atomicAdd(&gsum[cur * D + lane], acc);
            if (lane == 0) atomicAdd(&cnt[cur], (float)run);
            cur = bb; acc = 0.0f; run = 0;
        }
        acc += H[(size_t)i * D + lane];
        ++run;
    }
    atomicAdd(&gsum[cur * D + lane], acc);
    if (lane == 0) atomicAdd(&cnt[cur], (float)run);
}

// ---- out[b][c] = (gsum[b]/cnt[b]) @ linW + linb ----
__global__ void final_k(const float* __restrict__ gsum, const float* __restrict__ cnt,
                        const float* __restrict__ linW, const float* __restrict__ linb,
                        float* __restrict__ out) {
    int tid = blockIdx.x * 256 + threadIdx.x;
    if (tid >= N_GRAPHS * N_CLASSES) return;
    int b = tid / N_CLASSES, c = tid % N_CLASSES;
    float inv = 1.0f / fmaxf(cnt[b], 1.0f);
    float acc = linb[c];
#pragma unroll
    for (int k = 0; k < D; ++k)
        acc += gsum[b * D + k] * inv * linW[k * N_CLASSES + c];
    out[tid] = acc;
}

extern "C" void kernel_launch(void* const* d_in, const int* in_sizes, int n_in,
                              void* d_out, int out_size, void* d_ws, size_t ws_size,
                              hipStream_t stream) {
    const float* x    = (const float*)d_in[0];
    const int*   ei   = (const int*)  d_in[1];   // [2][E] int32
    const int*   batch= (const int*)  d_in[2];
    const float* W1   = (const float*)d_in[3];
    const float* b1   = (const float*)d_in[4];
    const float* W2   = (const float*)d_in[5];
    const float* b2   = (const float*)d_in[6];
    const float* W3   = (const float*)d_in[7];
    const float* b3   = (const float*)d_in[8];
    const float* linW = (const float*)d_in[9];
    const float* linb = (const float*)d_in[10];
    float* out = (float*)d_out;

    const int N = N_NODES, E = N_EDGES;
    const int* row = ei;
    const int* col = ei + E;

    // workspace layout (4B elements), ~57.3 MB total
    float* ws    = (float*)d_ws;
    float* dinv  = ws;                              // 100352
    int*   deg   = (int*)(dinv + 100352);           // 100352
    int*   cursor= deg + 100352;                    // 100352
    int*   csr   = cursor + 100352;                 // 1200128
    int*   total = csr + 1200128;                   // 64
    float* bufH  = (float*)(total + 64);            // 6.4M
    float* bufA  = bufH + (size_t)N * D;            // 6.4M
    float* gsum  = bufA + (size_t)N * D;            // 8192
    float* cnt   = gsum + N_GRAPHS * D;             // 128

    const int nb_nodes = (N + 255) / 256;           // 391
    const int nb_edges = (E + 255) / 256;           // 4688
    const int nb_gather= (N + 3) / 4;               // 25000
    const int nb_gemm  = 2048;                      // grid-stride
    const int nwaves   = (N + POOL_CHUNK - 1) / POOL_CHUNK;
    const int nb_pool  = (nwaves + 3) / 4;

    // CSR build (once, reused by all 3 layers)
    init_k<<<nb_nodes, 256, 0, stream>>>(deg, total, gsum, cnt, N);
    degcnt_k<<<nb_edges, 256, 0, stream>>>(col, deg, E);
    offsets_k<<<nb_nodes, 256, 0, stream>>>(deg, cursor, dinv, total, N);
    fill_k<<<nb_edges, 256, 0, stream>>>(row, col, cursor, csr, E);

    // layer 1
    gemm_k<<<nb_gemm, 256, 0, stream>>>(x, W1, dinv, bufH, N, 0);
    gather_k<<<nb_gather, 256, 0, stream>>>(bufH, csr, cursor, deg, dinv, b1, bufA, N);
    // layer 2
    gemm_k<<<nb_gemm, 256, 0, stream>>>(bufA, W2, dinv, bufH, N, 1);
    gather_k<<<nb_gather, 256, 0, stream>>>(bufH, csr, cursor, deg, dinv, b2, bufA, N);
    // layer 3
    gemm_k<<<nb_gemm, 256, 0, stream>>>(bufA, W3, dinv, bufH, N, 1);
    gather_k<<<nb_gather, 256, 0, stream>>>(bufH, csr, cursor, deg, dinv, b3, bufA, N);

    // pool + classify
    pool_k<<<nb_pool, 256, 0, stream>>>(bufA, batch, gsum, cnt, N);
    final_k<<<(N_GRAPHS * N_CLASSES + 255) / 256, 256, 0, stream>>>(gsum, cnt, linW, linb, out);
}

// Round 6
// 520.151 us; speedup vs baseline: 2.6159x; 1.1178x over previous
//
#include <hip/hip_runtime.h>
#include <hip/hip_bf16.h>

// GCN: 3x (GEMM 64x64 -> sym-norm gather via CSR) -> mean-pool -> linear.
// N=100000 nodes, E=1200000 edges, 128 graphs, D=64, classes=10.
// R2: CSR build (int atomics) + wave-per-node gather; dinv fused into GEMM.
// R6: pool_k 4x parallelism + shfl-broadcast batch (was 92us latency-bound,
//     3.7% occ); int4 edge loads in degcnt/fill; nontemporal csr store.

#define N_NODES 100000
#define N_EDGES 1200000
#define N_GRAPHS 128
#define D 64
#define N_CLASSES 10

// ---- init: zero deg_int, total counter, pool accumulators ----
__global__ void init_k(int* __restrict__ deg, int* __restrict__ total,
                       float* __restrict__ gsum, float* __restrict__ cnt, int n) {
    int i = blockIdx.x * 256 + threadIdx.x;
    if (i < n) deg[i] = 0;
    if (i == 0) *total = 0;
    if (i < N_GRAPHS * D) gsum[i] = 0.0f;
    if (i < N_GRAPHS) cnt[i] = 0.0f;
}

// ---- deg[c]++ per edge (int atomics, 4 edges/thread via int4) ----
__global__ void degcnt_k(const int4* __restrict__ col4, int* __restrict__ deg, int E4) {
    int t = blockIdx.x * 256 + threadIdx.x;
    if (t < E4) {
        int4 c = col4[t];
        atomicAdd(&deg[c.x], 1);
        atomicAdd(&deg[c.y], 1);
        atomicAdd(&deg[c.z], 1);
        atomicAdd(&deg[c.w], 1);
    }
}

// ---- per node: segment start via wave-scan + 1 atomic/wave; dinv ----
__global__ void offsets_k(const int* __restrict__ deg, int* __restrict__ cursor,
                          float* __restrict__ dinv, int* __restrict__ total, int n) {
    int i = blockIdx.x * 256 + threadIdx.x;
    int lane = threadIdx.x & 63;
    int v = (i < n) ? deg[i] : 0;
    int incl = v;
#pragma unroll
    for (int d = 1; d < 64; d <<= 1) {
        int t = __shfl_up(incl, d);
        if (lane >= d) incl += t;
    }
    int wsum = __shfl(incl, 63);
    int base = 0;
    if (lane == 63) base = atomicAdd(total, wsum);
    base = __shfl(base, 63);
    if (i < n) {
        cursor[i] = base + incl - v;                 // exclusive start
        dinv[i] = rsqrtf((float)(v + 1));            // +1 self loop
    }
}

// ---- fill CSR: csr[cursor[c]++] = r   (after this, cursor[c] = segment END) ----
__global__ void fill_k(const int4* __restrict__ row4, const int4* __restrict__ col4,
                       int* __restrict__ cursor, int* __restrict__ csr, int E4) {
    int t = blockIdx.x * 256 + threadIdx.x;
    if (t < E4) {
        int4 r = row4[t];
        int4 c = col4[t];
        int p0 = atomicAdd(&cursor[c.x], 1);
        __builtin_nontemporal_store(r.x, &csr[p0]);
        int p1 = atomicAdd(&cursor[c.y], 1);
        __builtin_nontemporal_store(r.y, &csr[p1]);
        int p2 = atomicAdd(&cursor[c.z], 1);
        __builtin_nontemporal_store(r.z, &csr[p2]);
        int p3 = atomicAdd(&cursor[c.w], 1);
        __builtin_nontemporal_store(r.w, &csr[p3]);
    }
}

// ---- H'[r][:] = (relu?(X[r]) @ W) * dinv[r] ----
// W[:,lane] held in 64 VGPRs (loaded once per block); X broadcast via LDS.
__global__ __launch_bounds__(256) void gemm_k(
        const float* __restrict__ X, const float* __restrict__ W,
        const float* __restrict__ dinv, float* __restrict__ H, int n, int relu_in) {
    __shared__ float Xs[4][D];
    int tid = threadIdx.x, wave = tid >> 6, lane = tid & 63;
    float wcol[D];
#pragma unroll
    for (int k = 0; k < D; ++k) wcol[k] = W[k * D + lane];
    for (int row0 = blockIdx.x * 4; row0 < n; row0 += gridDim.x * 4) {
        int row = row0 + wave;
        if (row < n) {
            float xv = X[row * D + lane];
            if (relu_in) xv = fmaxf(xv, 0.0f);
            Xs[wave][lane] = xv;
            float acc = 0.0f;
#pragma unroll
            for (int k = 0; k < D; ++k) acc += Xs[wave][k] * wcol[k];
            H[row * D + lane] = acc * dinv[row];
        }
    }
}

// ---- gather: O[c] = b + dinv[c] * (H'[c] + sum_{r in N(c)} H'[r]) ----
__global__ void gather_k(const float* __restrict__ Hp, const int* __restrict__ csr,
                         const int* __restrict__ cursor, const int* __restrict__ deg,
                         const float* __restrict__ dinv, const float* __restrict__ b,
                         float* __restrict__ O, int n) {
    int c = blockIdx.x * 4 + (threadIdx.x >> 6);
    if (c >= n) return;
    int lane = threadIdx.x & 63;
    int end = cursor[c];              // cursor == end after fill_k
    int dg = deg[c];
    int j = end - dg;
    float acc = Hp[(size_t)c * D + lane];   // self term (already * dinv[c])
    for (; j + 4 <= end; j += 4) {
        int s0 = csr[j], s1 = csr[j + 1], s2 = csr[j + 2], s3 = csr[j + 3];
        float v0 = Hp[(size_t)s0 * D + lane];
        float v1 = Hp[(size_t)s1 * D + lane];
        float v2 = Hp[(size_t)s2 * D + lane];
        float v3 = Hp[(size_t)s3 * D + lane];
        acc += v0 + v1 + v2 + v3;
    }
    for (; j < end; ++j) acc += Hp[(size_t)csr[j] * D + lane];
    O[(size_t)c * D + lane] = b[lane] + dinv[c] * acc;
}

// ---- mean-pool: wave per 64-node chunk; batch loaded once, shfl-broadcast ----
#define POOL_CHUNK 64
__global__ void pool_k(const float* __restrict__ H, const int* __restrict__ batch,
                       float* __restrict__ gsum, float* __restrict__ cnt, int n) {
    int wid = blockIdx.x * 4 + (threadIdx.x >> 6);
    int lane = threadIdx.x & 63;
    int start = wid * POOL_CHUNK;
    if (start >= n) return;
    int m = min(POOL_CHUNK, n - start);
    int bv = batch[min(start + lane, n - 1)];   // coalesced; lane k holds batch[start+k]
    int cur = __shfl(bv, 0);
    float acc = 0.0f;
    int run = 0;
    for (int k = 0; k < m; ++k) {
        int bb = __shfl(bv, k);
        if (bb != cur) {
            atomicAdd(&gsum[cur * D + lane], acc);
            if (lane == 0) atomicAdd(&cnt[cur], (float)run);
            cur = bb; acc = 0.0f; run = 0;
        }
        acc += H[(size_t)(start + k) * D + lane];
        ++run;
    }
    atomicAdd(&gsum[cur * D + lane], acc);
    if (lane == 0) atomicAdd(&cnt[cur], (float)run);
}

// ---- out[b][c] = (gsum[b]/cnt[b]) @ linW + linb ----
__global__ void final_k(const float* __restrict__ gsum, const float* __restrict__ cnt,
                        const float* __restrict__ linW, const float* __restrict__ linb,
                        float* __restrict__ out) {
    int tid = blockIdx.x * 256 + threadIdx.x;
    if (tid >= N_GRAPHS * N_CLASSES) return;
    int b = tid / N_CLASSES, c = tid % N_CLASSES;
    float inv = 1.0f / fmaxf(cnt[b], 1.0f);
    float acc = linb[c];
#pragma unroll
    for (int k = 0; k < D; ++k)
        acc += gsum[b * D + k] * inv * linW[k * N_CLASSES + c];
    out[tid] = acc;
}

extern "C" void kernel_launch(void* const* d_in, const int* in_sizes, int n_in,
                              void* d_out, int out_size, void* d_ws, size_t ws_size,
                              hipStream_t stream) {
    const float* x    = (const float*)d_in[0];
    const int*   ei   = (const int*)  d_in[1];   // [2][E] int32
    const int*   batch= (const int*)  d_in[2];
    const float* W1   = (const float*)d_in[3];
    const float* b1   = (const float*)d_in[4];
    const float* W2   = (const float*)d_in[5];
    const float* b2   = (const float*)d_in[6];
    const float* W3   = (const float*)d_in[7];
    const float* b3   = (const float*)d_in[8];
    const float* linW = (const float*)d_in[9];
    const float* linb = (const float*)d_in[10];
    float* out = (float*)d_out;

    const int N = N_NODES, E = N_EDGES, E4 = N_EDGES / 4;
    const int* row = ei;
    const int* col = ei + E;
    const int4* row4 = (const int4*)row;
    const int4* col4 = (const int4*)col;

    // workspace layout (4B elements), ~57.3 MB total
    float* ws    = (float*)d_ws;
    float* dinv  = ws;                              // 100352
    int*   deg   = (int*)(dinv + 100352);           // 100352
    int*   cursor= deg + 100352;                    // 100352
    int*   csr   = cursor + 100352;                 // 1200128
    int*   total = csr + 1200128;                   // 64
    float* bufH  = (float*)(total + 64);            // 6.4M
    float* bufA  = bufH + (size_t)N * D;            // 6.4M
    float* gsum  = bufA + (size_t)N * D;            // 8192
    float* cnt   = gsum + N_GRAPHS * D;             // 128

    const int nb_nodes = (N + 255) / 256;           // 391
    const int nb_e4    = (E4 + 255) / 256;          // 1172
    const int nb_gather= (N + 3) / 4;               // 25000
    const int nb_gemm  = 2048;                      // grid-stride
    const int nwaves   = (N + POOL_CHUNK - 1) / POOL_CHUNK;  // 1563
    const int nb_pool  = (nwaves + 3) / 4;          // 391

    // CSR build (once, reused by all 3 layers)
    init_k<<<nb_nodes, 256, 0, stream>>>(deg, total, gsum, cnt, N);
    degcnt_k<<<nb_e4, 256, 0, stream>>>(col4, deg, E4);
    offsets_k<<<nb_nodes, 256, 0, stream>>>(deg, cursor, dinv, total, N);
    fill_k<<<nb_e4, 256, 0, stream>>>(row4, col4, cursor, csr, E4);

    // layer 1
    gemm_k<<<nb_gemm, 256, 0, stream>>>(x, W1, dinv, bufH, N, 0);
    gather_k<<<nb_gather, 256, 0, stream>>>(bufH, csr, cursor, deg, dinv, b1, bufA, N);
    // layer 2
    gemm_k<<<nb_gemm, 256, 0, stream>>>(bufA, W2, dinv, bufH, N, 1);
    gather_k<<<nb_gather, 256, 0, stream>>>(bufH, csr, cursor, deg, dinv, b2, bufA, N);
    // layer 3
    gemm_k<<<nb_gemm, 256, 0, stream>>>(bufA, W3, dinv, bufH, N, 1);
    gather_k<<<nb_gather, 256, 0, stream>>>(bufH, csr, cursor, deg, dinv, b3, bufA, N);

    // pool + classify
    pool_k<<<nb_pool, 256, 0, stream>>>(bufA, batch, gsum, cnt, N);
    final_k<<<(N_GRAPHS * N_CLASSES + 255) / 256, 256, 0, stream>>>(gsum, cnt, linW, linb, out);
}

// Round 7
// 479.598 us; speedup vs baseline: 2.8371x; 1.0846x over previous
//
#include <hip/hip_runtime.h>
#include <hip/hip_bf16.h>

// GCN: 3x (GEMM 64x64 -> sym-norm gather via CSR) -> mean-pool -> linear.
// N=100000 nodes, E=1200000 edges, 128 graphs, D=64, classes=10.
// R2: CSR build (int atomics) + wave-per-node gather; dinv fused into GEMM.
// R6: pool_k 4x parallelism + shfl-broadcast batch; int4 edge loads.
// R7: H' staged as bf16 (gather reads halve: 307->154 MB/layer); csr segment
//     read via coalesced 64-wide load + shfl broadcast; revert nontemporal.

#define N_NODES 100000
#define N_EDGES 1200000
#define N_GRAPHS 128
#define D 64
#define N_CLASSES 10

typedef unsigned short ushort_t;

__device__ __forceinline__ float bf2f(ushort_t u) {
    union { unsigned int i; float f; } v;
    v.i = ((unsigned int)u) << 16;
    return v.f;
}

// ---- init: zero deg_int, total counter, pool accumulators ----
__global__ void init_k(int* __restrict__ deg, int* __restrict__ total,
                       float* __restrict__ gsum, float* __restrict__ cnt, int n) {
    int i = blockIdx.x * 256 + threadIdx.x;
    if (i < n) deg[i] = 0;
    if (i == 0) *total = 0;
    if (i < N_GRAPHS * D) gsum[i] = 0.0f;
    if (i < N_GRAPHS) cnt[i] = 0.0f;
}

// ---- deg[c]++ per edge (int atomics, 4 edges/thread via int4) ----
__global__ void degcnt_k(const int4* __restrict__ col4, int* __restrict__ deg, int E4) {
    int t = blockIdx.x * 256 + threadIdx.x;
    if (t < E4) {
        int4 c = col4[t];
        atomicAdd(&deg[c.x], 1);
        atomicAdd(&deg[c.y], 1);
        atomicAdd(&deg[c.z], 1);
        atomicAdd(&deg[c.w], 1);
    }
}

// ---- per node: segment start via wave-scan + 1 atomic/wave; dinv ----
__global__ void offsets_k(const int* __restrict__ deg, int* __restrict__ cursor,
                          float* __restrict__ dinv, int* __restrict__ total, int n) {
    int i = blockIdx.x * 256 + threadIdx.x;
    int lane = threadIdx.x & 63;
    int v = (i < n) ? deg[i] : 0;
    int incl = v;
#pragma unroll
    for (int d = 1; d < 64; d <<= 1) {
        int t = __shfl_up(incl, d);
        if (lane >= d) incl += t;
    }
    int wsum = __shfl(incl, 63);
    int base = 0;
    if (lane == 63) base = atomicAdd(total, wsum);
    base = __shfl(base, 63);
    if (i < n) {
        cursor[i] = base + incl - v;                 // exclusive start
        dinv[i] = rsqrtf((float)(v + 1));            // +1 self loop
    }
}

// ---- fill CSR: csr[cursor[c]++] = r   (after this, cursor[c] = segment END) ----
__global__ void fill_k(const int4* __restrict__ row4, const int4* __restrict__ col4,
                       int* __restrict__ cursor, int* __restrict__ csr, int E4) {
    int t = blockIdx.x * 256 + threadIdx.x;
    if (t < E4) {
        int4 r = row4[t];
        int4 c = col4[t];
        int p0 = atomicAdd(&cursor[c.x], 1);
        csr[p0] = r.x;
        int p1 = atomicAdd(&cursor[c.y], 1);
        csr[p1] = r.y;
        int p2 = atomicAdd(&cursor[c.z], 1);
        csr[p2] = r.z;
        int p3 = atomicAdd(&cursor[c.w], 1);
        csr[p3] = r.w;
    }
}

// ---- H'[r][:] = (relu?(X[r]) @ W) * dinv[r]  -> stored bf16 ----
// W[:,lane] held in 64 VGPRs (loaded once per block); X broadcast via LDS.
__global__ __launch_bounds__(256) void gemm_k(
        const float* __restrict__ X, const float* __restrict__ W,
        const float* __restrict__ dinv, ushort_t* __restrict__ H, int n, int relu_in) {
    __shared__ float Xs[4][D];
    int tid = threadIdx.x, wave = tid >> 6, lane = tid & 63;
    float wcol[D];
#pragma unroll
    for (int k = 0; k < D; ++k) wcol[k] = W[k * D + lane];
    for (int row0 = blockIdx.x * 4; row0 < n; row0 += gridDim.x * 4) {
        int row = row0 + wave;
        if (row < n) {
            float xv = X[row * D + lane];
            if (relu_in) xv = fmaxf(xv, 0.0f);
            Xs[wave][lane] = xv;
            float acc = 0.0f;
#pragma unroll
            for (int k = 0; k < D; ++k) acc += Xs[wave][k] * wcol[k];
            __hip_bfloat16 hb = __float2bfloat16(acc * dinv[row]);
            H[(size_t)row * D + lane] = *(ushort_t*)&hb;
        }
    }
}

// ---- gather: O[c] = b + dinv[c] * (H'[c] + sum_{r in N(c)} H'[r]) ----
// csr segment read 64-wide coalesced then shfl-broadcast; H' rows are bf16.
__global__ void gather_k(const ushort_t* __restrict__ Hp, const int* __restrict__ csr,
                         const int* __restrict__ cursor, const int* __restrict__ deg,
                         const float* __restrict__ dinv, const float* __restrict__ b,
                         float* __restrict__ O, int n) {
    int c = blockIdx.x * 4 + (threadIdx.x >> 6);
    if (c >= n) return;
    int lane = threadIdx.x & 63;
    int end = cursor[c];              // cursor == end after fill_k
    int dg = deg[c];
    float acc = bf2f(Hp[(size_t)c * D + lane]);   // self term (already * dinv[c])
    for (int j = end - dg; j < end; j += 64) {
        int idx = j + lane;
        int s = (idx < end) ? csr[idx] : 0;       // one coalesced load / 64 edges
        int cnt = min(64, end - j);
        int k = 0;
        for (; k + 4 <= cnt; k += 4) {
            int r0 = __shfl(s, k);
            int r1 = __shfl(s, k + 1);
            int r2 = __shfl(s, k + 2);
            int r3 = __shfl(s, k + 3);
            float v0 = bf2f(Hp[(size_t)r0 * D + lane]);
            float v1 = bf2f(Hp[(size_t)r1 * D + lane]);
            float v2 = bf2f(Hp[(size_t)r2 * D + lane]);
            float v3 = bf2f(Hp[(size_t)r3 * D + lane]);
            acc += v0 + v1 + v2 + v3;
        }
        for (; k < cnt; ++k) {
            int r0 = __shfl(s, k);
            acc += bf2f(Hp[(size_t)r0 * D + lane]);
        }
    }
    O[(size_t)c * D + lane] = b[lane] + dinv[c] * acc;
}

// ---- mean-pool: wave per 64-node chunk; batch loaded once, shfl-broadcast ----
#define POOL_CHUNK 64
__global__ void pool_k(const float* __restrict__ H, const int* __restrict__ batch,
                       float* __restrict__ gsum, float* __restrict__ cnt, int n) {
    int wid = blockIdx.x * 4 + (threadIdx.x >> 6);
    int lane = threadIdx.x & 63;
    int start = wid * POOL_CHUNK;
    if (start >= n) return;
    int m = min(POOL_CHUNK, n - start);
    int bv = batch[min(start + lane, n - 1)];   // coalesced; lane k holds batch[start+k]
    int cur = __shfl(bv, 0);
    float acc = 0.0f;
    int run = 0;
    for (int k = 0; k < m; ++k) {
        int bb = __shfl(bv, k);
        if (bb != cur) {
            atomicAdd(&gsum[cur * D + lane], acc);
            if (lane == 0) atomicAdd(&cnt[cur], (float)run);
            cur = bb; acc = 0.0f; run = 0;
        }
        acc += H[(size_t)(start + k) * D + lane];
        ++run;
    }
    atomicAdd(&gsum[cur * D + lane], acc);
    if (lane == 0) atomicAdd(&cnt[cur], (float)run);
}

// ---- out[b][c] = (gsum[b]/cnt[b]) @ linW + linb ----
__global__ void final_k(const float* __restrict__ gsum, const float* __restrict__ cnt,
                        const float* __restrict__ linW, const float* __restrict__ linb,
                        float* __restrict__ out) {
    int tid = blockIdx.x * 256 + threadIdx.x;
    if (tid >= N_GRAPHS * N_CLASSES) return;
    int b = tid / N_CLASSES, c = tid % N_CLASSES;
    float inv = 1.0f / fmaxf(cnt[b], 1.0f);
    float acc = linb[c];
#pragma unroll
    for (int k = 0; k < D; ++k)
        acc += gsum[b * D + k] * inv * linW[k * N_CLASSES + c];
    out[tid] = acc;
}

extern "C" void kernel_launch(void* const* d_in, const int* in_sizes, int n_in,
                              void* d_out, int out_size, void* d_ws, size_t ws_size,
                              hipStream_t stream) {
    const float* x    = (const float*)d_in[0];
    const int*   ei   = (const int*)  d_in[1];   // [2][E] int32
    const int*   batch= (const int*)  d_in[2];
    const float* W1   = (const float*)d_in[3];
    const float* b1   = (const float*)d_in[4];
    const float* W2   = (const float*)d_in[5];
    const float* b2   = (const float*)d_in[6];
    const float* W3   = (const float*)d_in[7];
    const float* b3   = (const float*)d_in[8];
    const float* linW = (const float*)d_in[9];
    const float* linb = (const float*)d_in[10];
    float* out = (float*)d_out;

    const int N = N_NODES, E = N_EDGES, E4 = N_EDGES / 4;
    const int* row = ei;
    const int* col = ei + E;
    const int4* row4 = (const int4*)row;
    const int4* col4 = (const int4*)col;

    // workspace layout (4B units kept from R6; bufH now holds bf16 in half of it)
    float* ws    = (float*)d_ws;
    float* dinv  = ws;                              // 100352
    int*   deg   = (int*)(dinv + 100352);           // 100352
    int*   cursor= deg + 100352;                    // 100352
    int*   csr   = cursor + 100352;                 // 1200128
    int*   total = csr + 1200128;                   // 64
    ushort_t* bufH = (ushort_t*)(total + 64);       // N*D bf16 (uses half region)
    float* bufA  = (float*)(total + 64) + (size_t)N * D;  // 6.4M f32
    float* gsum  = bufA + (size_t)N * D;            // 8192
    float* cnt   = gsum + N_GRAPHS * D;             // 128

    const int nb_nodes = (N + 255) / 256;           // 391
    const int nb_e4    = (E4 + 255) / 256;          // 1172
    const int nb_gather= (N + 3) / 4;               // 25000
    const int nb_gemm  = 2048;                      // grid-stride
    const int nwaves   = (N + POOL_CHUNK - 1) / POOL_CHUNK;  // 1563
    const int nb_pool  = (nwaves + 3) / 4;          // 391

    // CSR build (once, reused by all 3 layers)
    init_k<<<nb_nodes, 256, 0, stream>>>(deg, total, gsum, cnt, N);
    degcnt_k<<<nb_e4, 256, 0, stream>>>(col4, deg, E4);
    offsets_k<<<nb_nodes, 256, 0, stream>>>(deg, cursor, dinv, total, N);
    fill_k<<<nb_e4, 256, 0, stream>>>(row4, col4, cursor, csr, E4);

    // layer 1
    gemm_k<<<nb_gemm, 256, 0, stream>>>(x, W1, dinv, bufH, N, 0);
    gather_k<<<nb_gather, 256, 0, stream>>>(bufH, csr, cursor, deg, dinv, b1, bufA, N);
    // layer 2
    gemm_k<<<nb_gemm, 256, 0, stream>>>(bufA, W2, dinv, bufH, N, 1);
    gather_k<<<nb_gather, 256, 0, stream>>>(bufH, csr, cursor, deg, dinv, b2, bufA, N);
    // layer 3
    gemm_k<<<nb_gemm, 256, 0, stream>>>(bufA, W3, dinv, bufH, N, 1);
    gather_k<<<nb_gather, 256, 0, stream>>>(bufH, csr, cursor, deg, dinv, b3, bufA, N);

    // pool + classify
    pool_k<<<nb_pool, 256, 0, stream>>>(bufA, batch, gsum, cnt, N);
    final_k<<<(N_GRAPHS * N_CLASSES + 255) / 256, 256, 0, stream>>>(gsum, cnt, linW, linb, out);
}

// Round 8
// 362.231 us; speedup vs baseline: 3.7563x; 1.3240x over previous
//
#include <hip/hip_runtime.h>
#include <hip/hip_bf16.h>

// GCN: 3x (GEMM 64x64 -> sym-norm gather via CSR) -> mean-pool -> linear.
// N=100000 nodes, E=1200000 edges, 128 graphs, D=64, classes=10.
// R2: CSR + wave-per-node gather; dinv fused into GEMM.
// R6: pool_k 4x parallelism + shfl-broadcast batch; int4 edge loads.
// R7: H' staged as bf16 (gather reads halved); coalesced csr segment reads.
// R8: bucketed 2-level CSR build replaces degcnt/offsets/fill (fill_k wrote
//     85MB of partial lines for a 4.8MB csr; bucketed scatter writes merge
//     in L2). gather/gemm/pool/final byte-identical to R7.

#define N_NODES 100000
#define N_EDGES 1200000
#define N_GRAPHS 128
#define D 64
#define N_CLASSES 10

#define NB 512          // destination buckets
#define BSZ 196         // nodes per bucket (196*512 = 100352 >= N)
#define PEB 4096        // edges per partition block
#define PEB4 (PEB/4)

typedef unsigned short ushort_t;

__device__ __forceinline__ float bf2f(ushort_t u) {
    union { unsigned int i; float f; } v;
    v.i = ((unsigned int)u) << 16;
    return v.f;
}

// ---- init: zero bucket counts + pool accumulators ----
__global__ void init_k(int* __restrict__ bcount,
                       float* __restrict__ gsum, float* __restrict__ cnt) {
    int i = blockIdx.x * 256 + threadIdx.x;
    if (i < NB) bcount[i] = 0;
    if (i < N_GRAPHS * D) gsum[i] = 0.0f;
    if (i < N_GRAPHS) cnt[i] = 0.0f;
}

// ---- count: per-block LDS histogram of col/BSZ -> global bcount ----
__global__ void count_k(const int4* __restrict__ col4, int* __restrict__ bcount, int E4) {
    __shared__ int h[NB];
    for (int i = threadIdx.x; i < NB; i += 256) h[i] = 0;
    __syncthreads();
    int base = blockIdx.x * PEB4;
#pragma unroll
    for (int k = 0; k < 4; ++k) {
        int idx = base + k * 256 + threadIdx.x;
        if (idx < E4) {
            int4 c = col4[idx];
            atomicAdd(&h[c.x / BSZ], 1);
            atomicAdd(&h[c.y / BSZ], 1);
            atomicAdd(&h[c.z / BSZ], 1);
            atomicAdd(&h[c.w / BSZ], 1);
        }
    }
    __syncthreads();
    for (int i = threadIdx.x; i < NB; i += 256)
        if (h[i]) atomicAdd(&bcount[i], h[i]);
}

// ---- exclusive scan of bcount[512] -> bstart, bcursor (one block, 512 thr) ----
__global__ void scan_k(const int* __restrict__ bcount, int* __restrict__ bstart,
                       int* __restrict__ bcursor) {
    __shared__ int s[NB];
    int t = threadIdx.x;
    int v0 = bcount[t];
    s[t] = v0;
    __syncthreads();
    for (int off = 1; off < NB; off <<= 1) {
        int v = (t >= off) ? s[t - off] : 0;
        __syncthreads();
        s[t] += v;
        __syncthreads();
    }
    int ex = s[t] - v0;
    bstart[t] = ex;
    bcursor[t] = ex;
}

// ---- scatter edges into bucket-major int2 array (L2-mergeable writes) ----
__global__ void scatter_k(const int4* __restrict__ row4, const int4* __restrict__ col4,
                          int* __restrict__ bcursor, int2* __restrict__ part, int E4) {
    __shared__ int h[NB], gb[NB], c2[NB];
    for (int i = threadIdx.x; i < NB; i += 256) { h[i] = 0; c2[i] = 0; }
    __syncthreads();
    int base = blockIdx.x * PEB4;
    int4 rr[4], cc[4];
    bool ok[4];
#pragma unroll
    for (int k = 0; k < 4; ++k) {
        int idx = base + k * 256 + threadIdx.x;
        ok[k] = idx < E4;
        if (ok[k]) {
            rr[k] = row4[idx];
            cc[k] = col4[idx];
            atomicAdd(&h[cc[k].x / BSZ], 1);
            atomicAdd(&h[cc[k].y / BSZ], 1);
            atomicAdd(&h[cc[k].z / BSZ], 1);
            atomicAdd(&h[cc[k].w / BSZ], 1);
        }
    }
    __syncthreads();
    for (int i = threadIdx.x; i < NB; i += 256)
        if (h[i]) gb[i] = atomicAdd(&bcursor[i], h[i]);
    __syncthreads();
#pragma unroll
    for (int k = 0; k < 4; ++k) {
        if (ok[k]) {
            int r[4] = { rr[k].x, rr[k].y, rr[k].z, rr[k].w };
            int c[4] = { cc[k].x, cc[k].y, cc[k].z, cc[k].w };
#pragma unroll
            for (int j = 0; j < 4; ++j) {
                int b = c[j] / BSZ;
                int rk = atomicAdd(&c2[b], 1);
                part[gb[b] + rk] = make_int2(r[j], c[j]);
            }
        }
    }
}

// ---- per-bucket counting sort in LDS: write csr segment + deg/dinv/cursor ----
__global__ void sortbuild_k(const int2* __restrict__ part, const int* __restrict__ bstart,
                            const int* __restrict__ bcount, int* __restrict__ csr,
                            int* __restrict__ deg, int* __restrict__ cursor,
                            float* __restrict__ dinv) {
    __shared__ int h[256], st[256], c2[256];
    int b = blockIdx.x, t = threadIdx.x;
    int ebeg = bstart[b];
    int cntE = bcount[b];
    h[t] = 0; c2[t] = 0;
    __syncthreads();
    for (int e = ebeg + t; e < ebeg + cntE; e += 256) {
        int2 rc = part[e];
        atomicAdd(&h[rc.y - b * BSZ], 1);
    }
    __syncthreads();
    int hv = h[t];
    // inclusive Hillis-Steele scan over 256 entries
    for (int off = 1; off < 256; off <<= 1) {
        int v = (t >= off) ? h[t - off] : 0;
        __syncthreads();
        h[t] += v;
        __syncthreads();
    }
    st[t] = h[t] - hv;   // exclusive local start
    __syncthreads();
    int node = b * BSZ + t;
    if (t < BSZ && node < N_NODES) {
        deg[node] = hv;
        dinv[node] = rsqrtf((float)(hv + 1));
        cursor[node] = ebeg + st[t] + hv;   // global segment END
    }
    for (int e = ebeg + t; e < ebeg + cntE; e += 256) {
        int2 rc = part[e];
        int cl = rc.y - b * BSZ;
        int rk = atomicAdd(&c2[cl], 1);
        csr[ebeg + st[cl] + rk] = rc.x;
    }
}

// ---- H'[r][:] = (relu?(X[r]) @ W) * dinv[r]  -> stored bf16 ----
__global__ __launch_bounds__(256) void gemm_k(
        const float* __restrict__ X, const float* __restrict__ W,
        const float* __restrict__ dinv, ushort_t* __restrict__ H, int n, int relu_in) {
    __shared__ float Xs[4][D];
    int tid = threadIdx.x, wave = tid >> 6, lane = tid & 63;
    float wcol[D];
#pragma unroll
    for (int k = 0; k < D; ++k) wcol[k] = W[k * D + lane];
    for (int row0 = blockIdx.x * 4; row0 < n; row0 += gridDim.x * 4) {
        int row = row0 + wave;
        if (row < n) {
            float xv = X[row * D + lane];
            if (relu_in) xv = fmaxf(xv, 0.0f);
            Xs[wave][lane] = xv;
            float acc = 0.0f;
#pragma unroll
            for (int k = 0; k < D; ++k) acc += Xs[wave][k] * wcol[k];
            __hip_bfloat16 hb = __float2bfloat16(acc * dinv[row]);
            H[(size_t)row * D + lane] = *(ushort_t*)&hb;
        }
    }
}

// ---- gather: O[c] = b + dinv[c] * (H'[c] + sum_{r in N(c)} H'[r]) ----
__global__ void gather_k(const ushort_t* __restrict__ Hp, const int* __restrict__ csr,
                         const int* __restrict__ cursor, const int* __restrict__ deg,
                         const float* __restrict__ dinv, const float* __restrict__ b,
                         float* __restrict__ O, int n) {
    int c = blockIdx.x * 4 + (threadIdx.x >> 6);
    if (c >= n) return;
    int lane = threadIdx.x & 63;
    int end = cursor[c];
    int dg = deg[c];
    float acc = bf2f(Hp[(size_t)c * D + lane]);
    for (int j = end - dg; j < end; j += 64) {
        int idx = j + lane;
        int s = (idx < end) ? csr[idx] : 0;
        int cnt = min(64, end - j);
        int k = 0;
        for (; k + 4 <= cnt; k += 4) {
            int r0 = __shfl(s, k);
            int r1 = __shfl(s, k + 1);
            int r2 = __shfl(s, k + 2);
            int r3 = __shfl(s, k + 3);
            float v0 = bf2f(Hp[(size_t)r0 * D + lane]);
            float v1 = bf2f(Hp[(size_t)r1 * D + lane]);
            float v2 = bf2f(Hp[(size_t)r2 * D + lane]);
            float v3 = bf2f(Hp[(size_t)r3 * D + lane]);
            acc += v0 + v1 + v2 + v3;
        }
        for (; k < cnt; ++k) {
            int r0 = __shfl(s, k);
            acc += bf2f(Hp[(size_t)r0 * D + lane]);
        }
    }
    O[(size_t)c * D + lane] = b[lane] + dinv[c] * acc;
}

// ---- mean-pool: wave per 64-node chunk; batch loaded once, shfl-broadcast ----
#define POOL_CHUNK 64
__global__ void pool_k(const float* __restrict__ H, const int* __restrict__ batch,
                       float* __restrict__ gsum, float* __restrict__ cnt, int n) {
    int wid = blockIdx.x * 4 + (threadIdx.x >> 6);
    int lane = threadIdx.x & 63;
    int start = wid * POOL_CHUNK;
    if (start >= n) return;
    int m = min(POOL_CHUNK, n - start);
    int bv = batch[min(start + lane, n - 1)];
    int cur = __shfl(bv, 0);
    float acc = 0.0f;
    int run = 0;
    for (int k = 0; k < m; ++k) {
        int bb = __shfl(bv, k);
        if (bb != cur) {
            atomicAdd(&gsum[cur * D + lane], acc);
            if (lane == 0) atomicAdd(&cnt[cur], (float)run);
            cur = bb; acc = 0.0f; run = 0;
        }
        acc += H[(size_t)(start + k) * D + lane];
        ++run;
    }
    atomicAdd(&gsum[cur * D + lane], acc);
    if (lane == 0) atomicAdd(&cnt[cur], (float)run);
}

// ---- out[b][c] = (gsum[b]/cnt[b]) @ linW + linb ----
__global__ void final_k(const float* __restrict__ gsum, const float* __restrict__ cnt,
                        const float* __restrict__ linW, const float* __restrict__ linb,
                        float* __restrict__ out) {
    int tid = blockIdx.x * 256 + threadIdx.x;
    if (tid >= N_GRAPHS * N_CLASSES) return;
    int b = tid / N_CLASSES, c = tid % N_CLASSES;
    float inv = 1.0f / fmaxf(cnt[b], 1.0f);
    float acc = linb[c];
#pragma unroll
    for (int k = 0; k < D; ++k)
        acc += gsum[b * D + k] * inv * linW[k * N_CLASSES + c];
    out[tid] = acc;
}

extern "C" void kernel_launch(void* const* d_in, const int* in_sizes, int n_in,
                              void* d_out, int out_size, void* d_ws, size_t ws_size,
                              hipStream_t stream) {
    const float* x    = (const float*)d_in[0];
    const int*   ei   = (const int*)  d_in[1];
    const int*   batch= (const int*)  d_in[2];
    const float* W1   = (const float*)d_in[3];
    const float* b1   = (const float*)d_in[4];
    const float* W2   = (const float*)d_in[5];
    const float* b2   = (const float*)d_in[6];
    const float* W3   = (const float*)d_in[7];
    const float* b3   = (const float*)d_in[8];
    const float* linW = (const float*)d_in[9];
    const float* linb = (const float*)d_in[10];
    float* out = (float*)d_out;

    const int N = N_NODES, E = N_EDGES, E4 = N_EDGES / 4;
    const int4* row4 = (const int4*)ei;
    const int4* col4 = (const int4*)(ei + E);

    // workspace layout (int units)
    int* wsi = (int*)d_ws;
    float* dinv   = (float*)wsi;                    // 100352
    int*   deg    = wsi + 100352;                   // 100352
    int*   cursor = deg + 100352;                   // 100352
    int*   csr    = cursor + 100352;                // 1200128
    int*   bcount = csr + 1200128;                  // 512
    int*   bstart = bcount + 512;                   // 512
    int*   bcursor= bstart + 512;                   // 512
    int2*  part   = (int2*)(bcursor + 512);         // 1200128 int2 (9.6MB)
    ushort_t* bufH = (ushort_t*)(part + 1200128);   // N*D bf16 (12.8MB)
    float* bufA   = (float*)(bufH + (size_t)N * D); // N*D f32 (25.6MB)
    float* gsum   = bufA + (size_t)N * D;           // 8192
    float* cnt    = gsum + N_GRAPHS * D;            // 128

    const int nb_part  = (E + PEB - 1) / PEB;       // 293
    const int nb_gather= (N + 3) / 4;               // 25000
    const int nb_gemm  = 2048;
    const int nwaves   = (N + POOL_CHUNK - 1) / POOL_CHUNK;
    const int nb_pool  = (nwaves + 3) / 4;

    // bucketed CSR build
    init_k<<<(N_GRAPHS * D + 255) / 256, 256, 0, stream>>>(bcount, gsum, cnt);
    count_k<<<nb_part, 256, 0, stream>>>(col4, bcount, E4);
    scan_k<<<1, NB, 0, stream>>>(bcount, bstart, bcursor);
    scatter_k<<<nb_part, 256, 0, stream>>>(row4, col4, bcursor, part, E4);
    sortbuild_k<<<NB, 256, 0, stream>>>(part, bstart, bcount, csr, deg, cursor, dinv);

    // layer 1
    gemm_k<<<nb_gemm, 256, 0, stream>>>(x, W1, dinv, bufH, N, 0);
    gather_k<<<nb_gather, 256, 0, stream>>>(bufH, csr, cursor, deg, dinv, b1, bufA, N);
    // layer 2
    gemm_k<<<nb_gemm, 256, 0, stream>>>(bufA, W2, dinv, bufH, N, 1);
    gather_k<<<nb_gather, 256, 0, stream>>>(bufH, csr, cursor, deg, dinv, b2, bufA, N);
    // layer 3
    gemm_k<<<nb_gemm, 256, 0, stream>>>(bufA, W3, dinv, bufH, N, 1);
    gather_k<<<nb_gather, 256, 0, stream>>>(bufH, csr, cursor, deg, dinv, b3, bufA, N);

    // pool + classify
    pool_k<<<nb_pool, 256, 0, stream>>>(bufA, batch, gsum, cnt, N);
    final_k<<<(N_GRAPHS * N_CLASSES + 255) / 256, 256, 0, stream>>>(gsum, cnt, linW, linb, out);
}